// Round 5
// baseline (268.589 us; speedup 1.0000x reference)
//
#include <hip/hip_runtime.h>

// Problem constants
#define B_  2
#define N_  2048
#define M_  2048
#define D_  1024
#define H_  16
#define DH_ 64

typedef __bf16 bf16x8 __attribute__((ext_vector_type(8)));
typedef __bf16 bf16x4 __attribute__((ext_vector_type(4)));
typedef short  short4v __attribute__((ext_vector_type(4)));
typedef float  f32x4  __attribute__((ext_vector_type(4)));
typedef unsigned int u32x4v __attribute__((ext_vector_type(4)));

#define GAS(p) ((__attribute__((address_space(1))) void*)(p))
#define LAS(p) ((__attribute__((address_space(3))) void*)(p))

// SCALE * log2(e), folded into Q at projection time
#define QPRESCALE 0.18033688011112042f

__device__ __forceinline__ unsigned short f2bf(float f) {
    unsigned int u = __builtin_bit_cast(unsigned int, f);
    u += 0x7fffu + ((u >> 16) & 1u);   // round-to-nearest-even
    return (unsigned short)(u >> 16);
}

// pack two f32 -> one u32 of 2 bf16 (lo = a, hi = b), RNE
__device__ __forceinline__ unsigned cvtpkbf(float a, float b) {
    unsigned r;
    asm("v_cvt_pk_bf16_f32 %0, %1, %2" : "=v"(r) : "v"(a), "v"(b));
    return r;
}

// ------- kernel 1: prep = weight transpose+cast (z<4) | input cast (z==4) -------
__global__ __launch_bounds__(256) void prep(
    const float* __restrict__ x, const float* __restrict__ ctx,
    const float* __restrict__ Wq, const float* __restrict__ Wk,
    const float* __restrict__ Wv, const float* __restrict__ Wo,
    unsigned short* __restrict__ xb, unsigned short* __restrict__ cb,
    unsigned short* __restrict__ WTbase)
{
    if (blockIdx.z == 4) {
        int blk = blockIdx.y * 32 + blockIdx.x;
        int stride = 1024 * 256;
        for (int i = blk * 256 + threadIdx.x; i < 2097152; i += stride) {
            const float4* src; unsigned short* dst; int j;
            if (i < 1048576) { src = (const float4*)x;   dst = xb; j = i; }
            else             { src = (const float4*)ctx; dst = cb; j = i - 1048576; }
            float4 v = src[j];
            ushort4 o = make_ushort4(f2bf(v.x), f2bf(v.y), f2bf(v.z), f2bf(v.w));
            *(ushort4*)(dst + 4*j) = o;
        }
        return;
    }
    const float* W = (blockIdx.z == 0) ? Wq : (blockIdx.z == 1) ? Wk
                    : (blockIdx.z == 2) ? Wv : Wo;
    unsigned short* WT = WTbase + (size_t)blockIdx.z * 1048576;
    __shared__ unsigned short t[32][33];
    int tx = threadIdx.x & 31, ty8 = threadIdx.x >> 5;   // 32 x 8
    int c = blockIdx.x * 32 + tx;
#pragma unroll
    for (int i = 0; i < 4; ++i) {
        int r = blockIdx.y * 32 + i*8 + ty8;
        t[i*8 + ty8][tx] = f2bf(W[(size_t)r * 1024 + c]);
    }
    __syncthreads();
    int c2 = blockIdx.y * 32 + tx;
#pragma unroll
    for (int i = 0; i < 4; ++i) {
        int r2 = blockIdx.x * 32 + i*8 + ty8;
        WT[(size_t)r2 * 1024 + c2] = t[tx][i*8 + ty8];
    }
}

// ---------------- kernel 2: 128x128 bf16 GEMM, C = A * Bt^T (QKV modes) -------
// mode 0: A=WqT, Bt=xb  -> Q^T tile, stored [B,H,N,64] bf16 (*QPRESCALE), ushort4
// mode 1: A=WkT, Bt=cb  -> K^T tile, stored [B,H,M,64] bf16, ushort4
// mode 2: A=cb,  Bt=WvT -> V^T stored [B,H,64,M] bf16, ushort4 (original swap)
__global__ __launch_bounds__(256) void gemm128(
    const unsigned short* __restrict__ xb,
    const unsigned short* __restrict__ cb,
    const unsigned short* __restrict__ wT,
    const unsigned short* __restrict__ aoA,
    unsigned short* __restrict__ qkv_out,
    const float* __restrict__ bo,
    float* __restrict__ outF,
    int base_mode)
{
    __shared__ __align__(16) unsigned short As[128*32];
    __shared__ __align__(16) unsigned short Bs[128*32];

    const int mode = base_mode + blockIdx.z;
    const unsigned short* Amat;
    const unsigned short* Bt;
    if (mode == 0)      { Amat = wT;               Bt = xb; }
    else if (mode == 1) { Amat = wT + 1048576;     Bt = cb; }
    else if (mode == 2) { Amat = cb;               Bt = wT + 2*1048576; }
    else                { Amat = wT + 3*1048576;   Bt = aoA; }

    const int tid = threadIdx.x;
    const int w = tid >> 6, l = tid & 63;
    const int quad = l >> 4, l16 = l & 15;
    const int wm = w & 1, wn = w >> 1;
    int row0, col0;
    if (mode == 2) { row0 = blockIdx.x * 128; col0 = blockIdx.y * 128; }
    else           { row0 = blockIdx.y * 128; col0 = blockIdx.x * 128; }

    f32x4 acc[4][4];
#pragma unroll
    for (int i = 0; i < 4; ++i)
#pragma unroll
        for (int j = 0; j < 4; ++j) acc[i][j] = (f32x4){0.f, 0.f, 0.f, 0.f};

    for (int k0 = 0; k0 < 1024; k0 += 32) {
        __syncthreads();
#pragma unroll
        for (int i = 0; i < 2; ++i) {
            int s = i*256 + w*64 + l;
            int m = s >> 2, c = s & 3;
            int cs = c ^ ((m >> 1) & 3);
            __builtin_amdgcn_global_load_lds(
                GAS(Amat + (size_t)(row0 + m)*1024 + k0 + cs*8),
                LAS(As + (i*256 + w*64)*8), 16, 0, 0);
            __builtin_amdgcn_global_load_lds(
                GAS(Bt + (size_t)(col0 + m)*1024 + k0 + cs*8),
                LAS(Bs + (i*256 + w*64)*8), 16, 0, 0);
        }
        __syncthreads();

        bf16x8 af[4], bfr[4];
#pragma unroll
        for (int mt = 0; mt < 4; ++mt) {
            int m = wm*64 + mt*16 + l16;
            af[mt] = *reinterpret_cast<const bf16x8*>(As + m*32 + (quad ^ ((m >> 1) & 3))*8);
            int n = wn*64 + mt*16 + l16;
            bfr[mt] = *reinterpret_cast<const bf16x8*>(Bs + n*32 + (quad ^ ((n >> 1) & 3))*8);
        }
#pragma unroll
        for (int mt = 0; mt < 4; ++mt)
#pragma unroll
            for (int nt = 0; nt < 4; ++nt)
                acc[mt][nt] = __builtin_amdgcn_mfma_f32_16x16x32_bf16(
                    af[mt], bfr[nt], acc[mt][nt], 0, 0, 0);
    }

    // Epilogues.  C/D layout: col = l16, row = quad*4 + r  [m89/m91 verified]
    if (mode == 2) {
        // V^T: [B,H,64,M]; r-direction = token n -> ushort4
#pragma unroll
        for (int mt = 0; mt < 4; ++mt) {
            int gr = row0 + wm*64 + mt*16 + quad*4;
            int b = gr >> 11, nidx = gr & 2047;
#pragma unroll
            for (int nt = 0; nt < 4; ++nt) {
                int col = col0 + wn*64 + nt*16 + l16;
                int h = col >> 6, d = col & 63;
                ushort4 pk = make_ushort4(f2bf(acc[mt][nt][0]), f2bf(acc[mt][nt][1]),
                                          f2bf(acc[mt][nt][2]), f2bf(acc[mt][nt][3]));
                *(ushort4*)(qkv_out + (size_t)2*4194304
                            + (size_t)((b*16 + h)*64 + d)*2048 + nidx) = pk;
            }
        }
    } else {
        // Q^T/K^T tile: row = channel c=(h,d) (4 consecutive d), col = token n
        const float qs = (mode == 0) ? QPRESCALE : 1.0f;
        unsigned short* obase = qkv_out + (size_t)mode*4194304;
#pragma unroll
        for (int nt = 0; nt < 4; ++nt) {
            int n = col0 + wn*64 + nt*16 + l16;
            int b = n >> 11, nidx = n & 2047;
#pragma unroll
            for (int mt = 0; mt < 4; ++mt) {
                int c = row0 + wm*64 + mt*16 + quad*4;
                int h = c >> 6, d = c & 63;
                ushort4 pkv = make_ushort4(
                    f2bf(acc[mt][nt][0] * qs), f2bf(acc[mt][nt][1] * qs),
                    f2bf(acc[mt][nt][2] * qs), f2bf(acc[mt][nt][3] * qs));
                *(ushort4*)(obase + (size_t)((b*16 + h)*2048 + nidx)*64 + d) = pkv;
            }
        }
    }
}

// ---------------- kernel 2b: out-projection GEMM, 64x128 tile -----------------
__global__ __launch_bounds__(256) void gemm_out(
    const unsigned short* __restrict__ woT,  // [1024 out-ch][1024 in] bf16
    const unsigned short* __restrict__ aoA,  // [4096 tokens][1024] bf16
    const float* __restrict__ bo,
    float* __restrict__ outF)                // [4096 tokens][1024] f32
{
    __shared__ __align__(16) unsigned short As[64*32];
    __shared__ __align__(16) unsigned short Bs[128*32];

    const int tid = threadIdx.x;
    const int w = tid >> 6, l = tid & 63;
    const int quad = l >> 4, l16 = l & 15;
    const int row0 = blockIdx.y * 64;    // out-channel tile
    const int col0 = blockIdx.x * 128;   // token tile

    f32x4 acc[4][2];
#pragma unroll
    for (int i = 0; i < 4; ++i)
#pragma unroll
        for (int j = 0; j < 2; ++j) acc[i][j] = (f32x4){0.f, 0.f, 0.f, 0.f};

    for (int k0 = 0; k0 < 1024; k0 += 32) {
        __syncthreads();
        {
            int m = tid >> 2, c = tid & 3;
            int cs = c ^ ((m >> 1) & 3);
            __builtin_amdgcn_global_load_lds(
                GAS(woT + (size_t)(row0 + m)*1024 + k0 + cs*8),
                LAS(As + (w*64)*8), 16, 0, 0);
        }
#pragma unroll
        for (int i = 0; i < 2; ++i) {
            int s = i*256 + tid;
            int m = s >> 2, c = s & 3;
            int cs = c ^ ((m >> 1) & 3);
            __builtin_amdgcn_global_load_lds(
                GAS(aoA + (size_t)(col0 + m)*1024 + k0 + cs*8),
                LAS(Bs + (i*256 + w*64)*8), 16, 0, 0);
        }
        __syncthreads();

        bf16x8 af[4], bfr[2];
#pragma unroll
        for (int mt = 0; mt < 4; ++mt) {
            int m = mt*16 + l16;
            af[mt] = *reinterpret_cast<const bf16x8*>(As + m*32 + (quad ^ ((m >> 1) & 3))*8);
        }
#pragma unroll
        for (int nt = 0; nt < 2; ++nt) {
            int n = w*32 + nt*16 + l16;
            bfr[nt] = *reinterpret_cast<const bf16x8*>(Bs + n*32 + (quad ^ ((n >> 1) & 3))*8);
        }
#pragma unroll
        for (int mt = 0; mt < 4; ++mt)
#pragma unroll
            for (int nt = 0; nt < 2; ++nt)
                acc[mt][nt] = __builtin_amdgcn_mfma_f32_16x16x32_bf16(
                    af[mt], bfr[nt], acc[mt][nt], 0, 0, 0);
    }

#pragma unroll
    for (int mt = 0; mt < 4; ++mt) {
        int c = row0 + mt*16 + quad*4;
        float4 bv = *(const float4*)(bo + c);
#pragma unroll
        for (int nt = 0; nt < 2; ++nt) {
            int n = col0 + w*32 + nt*16 + l16;
            float4 ov = make_float4(acc[mt][nt][0] + bv.x, acc[mt][nt][1] + bv.y,
                                    acc[mt][nt][2] + bv.z, acc[mt][nt][3] + bv.w);
            *(float4*)(outF + (size_t)n*1024 + c) = ov;
        }
    }
}

// ---------------- kernel 3: flash attention (LDS-free, round-5) ----------------
// ROUND CHANGE (reg-direct K/V): per-CU pipe tally showed LDS was ~52% of the
// iteration wall (131 KB/CU-iter of ds_read_b128 + 512 conflict-cyc), while
// all 4 waves of a block read IDENTICAL K/V fragments that are L2-resident
// (KV working set per XCD ~2-4 MB < 4 MB L2).  The global->LDS->reg round
// trip buys nothing over L2.  Now K and V fragments are loaded DIRECTLY
// global->register: K double-buffered (prefetch K(t+1) issued after QK(t),
// covered by softmax+PV), V single-buffered (issued at tile top, covered by
// QK+softmax).  No LDS, no barriers -- waves fully independent.  Static reg
// indexing via inlined tile fn + 2x-unrolled ping-pong (rule #20).
// Each load instr reads 16 fully-used 64B lines; total L2 read ~1.07 GB
// (~26 TB/s at predicted dur, 74% of L2 ceiling).
__global__ __launch_bounds__(256, 2) void flash_attn(
    const unsigned short* __restrict__ qw,   // [B,H,N,64]  (pre-scaled)
    const unsigned short* __restrict__ kw,   // [B,H,M,64]
    const unsigned short* __restrict__ vtw,  // [B,H,64,M]
    unsigned short* __restrict__ ao)         // [B,N,H*64]
{
    const int tid = threadIdx.x;
    const int w = tid >> 6, l = tid & 63;
    const int quad = l >> 4, l16 = l & 15;
    const int bh = blockIdx.z * H_ + blockIdx.y;
    const int q0 = blockIdx.x * 128 + w * 32;   // this wave's 32 queries

    const unsigned short* kbase = kw + (size_t)bh*131072;
    const unsigned short* vbase = vtw + (size_t)bh*131072;
    // per-lane fragment bases
    const unsigned short* kf_base = kbase + (size_t)l16*64 + quad*8;
    const unsigned short* vf_base = vbase + (size_t)l16*2048 + quad*8;

    // Q as B-frag (K=32): B[n=q][k=d]; two 16-q groups
    bf16x8 qf[2][2];
#pragma unroll
    for (int qg = 0; qg < 2; ++qg)
#pragma unroll
        for (int s = 0; s < 2; ++s)
            qf[qg][s] = *reinterpret_cast<const bf16x8*>(
                qw + (size_t)(bh*2048 + q0 + qg*16 + l16)*64 + s*32 + quad*8);

    f32x4 accO[2][4];
#pragma unroll
    for (int qg = 0; qg < 2; ++qg)
#pragma unroll
        for (int td = 0; td < 4; ++td) accO[qg][td] = (f32x4){0.f, 0.f, 0.f, 0.f};
    float lpart[2] = {0.f, 0.f};

    const f32x4 zz = (f32x4){0.f, 0.f, 0.f, 0.f};

    // K register tiles (double-buffered): frag element = K[it*64+t*16+l16][kh*32+quad*8+e]
    bf16x8 kA[4][2], kB[4][2];

    auto load_k = [&](int it, bf16x8 (&kd)[4][2]) {
#pragma unroll
        for (int t = 0; t < 4; ++t)
#pragma unroll
            for (int kh = 0; kh < 2; ++kh)
                kd[t][kh] = *reinterpret_cast<const bf16x8*>(
                    kf_base + (size_t)(it*64 + t*16)*64 + kh*32);
    };

    // one KV tile: V loads issued first (covered by QK+softmax), K(it+1)
    // prefetch issued right after QK (covered by softmax+PV).
    auto tile = [&](int it, bf16x8 (&kC)[4][2], bf16x8 (&kN)[4][2]) {
        // V frags: element = V^T[td*16+l16][it*64 + t2*32 + quad*8 + e]
        bf16x8 vb[4][2];
#pragma unroll
        for (int td = 0; td < 4; ++td)
#pragma unroll
            for (int t2 = 0; t2 < 2; ++t2)
                vb[td][t2] = *reinterpret_cast<const bf16x8*>(
                    vf_base + (size_t)td*32768 + it*64 + t2*32);

        // S^T = K Q^T : A = K-frag (m=kv), B = Q-frag (n=q)
        f32x4 sac[2][4];
        __builtin_amdgcn_s_setprio(1);
#pragma unroll
        for (int t = 0; t < 4; ++t) {
            sac[0][t] = __builtin_amdgcn_mfma_f32_16x16x32_bf16(kC[t][0], qf[0][0], zz, 0, 0, 0);
            sac[1][t] = __builtin_amdgcn_mfma_f32_16x16x32_bf16(kC[t][0], qf[1][0], zz, 0, 0, 0);
            sac[0][t] = __builtin_amdgcn_mfma_f32_16x16x32_bf16(kC[t][1], qf[0][1], sac[0][t], 0, 0, 0);
            sac[1][t] = __builtin_amdgcn_mfma_f32_16x16x32_bf16(kC[t][1], qf[1][1], sac[1][t], 0, 0, 0);
        }
        __builtin_amdgcn_s_setprio(0);

        // prefetch next K tile into the other buffer
        if (it + 1 < 32) load_k(it + 1, kN);

        // P^T = exp2(S^T); per-lane fp32 partial row-sums; build K=32 B-frags
        u32x4v pB[2][2];
#pragma unroll
        for (int qg = 0; qg < 2; ++qg) {
            float s0 = 0.f, s1 = 0.f, s2 = 0.f, s3 = 0.f;
#pragma unroll
            for (int t2 = 0; t2 < 2; ++t2) {
                float pe0 = __builtin_amdgcn_exp2f(sac[qg][2*t2][0]);
                float pe1 = __builtin_amdgcn_exp2f(sac[qg][2*t2][1]);
                float pe2 = __builtin_amdgcn_exp2f(sac[qg][2*t2][2]);
                float pe3 = __builtin_amdgcn_exp2f(sac[qg][2*t2][3]);
                float po0 = __builtin_amdgcn_exp2f(sac[qg][2*t2+1][0]);
                float po1 = __builtin_amdgcn_exp2f(sac[qg][2*t2+1][1]);
                float po2 = __builtin_amdgcn_exp2f(sac[qg][2*t2+1][2]);
                float po3 = __builtin_amdgcn_exp2f(sac[qg][2*t2+1][3]);
                s0 += pe0 + po0; s1 += pe1 + po1;
                s2 += pe2 + po2; s3 += pe3 + po3;
                unsigned b0 = cvtpkbf(pe0, pe1), b1 = cvtpkbf(pe2, pe3);
                unsigned b2 = cvtpkbf(po0, po1), b3 = cvtpkbf(po2, po3);
                asm("v_permlane32_swap_b32 %0, %1" : "+v"(b0), "+v"(b2));
                asm("v_permlane16_swap_b32 %0, %1" : "+v"(b0), "+v"(b2));
                asm("v_permlane32_swap_b32 %0, %1" : "+v"(b1), "+v"(b3));
                asm("v_permlane16_swap_b32 %0, %1" : "+v"(b1), "+v"(b3));
                pB[qg][t2] = (u32x4v){b0, b1, b2, b3};
            }
            lpart[qg] += (s0 + s1) + (s2 + s3);
        }

        // O^T += V^T P^T : A = V^T-frag (m=d, k=kv, K=32), B = P^T (registers)
        __builtin_amdgcn_s_setprio(1);
#pragma unroll
        for (int td = 0; td < 4; ++td) {
#pragma unroll
            for (int t2 = 0; t2 < 2; ++t2) {
                accO[0][td] = __builtin_amdgcn_mfma_f32_16x16x32_bf16(
                    vb[td][t2], __builtin_bit_cast(bf16x8, pB[0][t2]), accO[0][td], 0, 0, 0);
                accO[1][td] = __builtin_amdgcn_mfma_f32_16x16x32_bf16(
                    vb[td][t2], __builtin_bit_cast(bf16x8, pB[1][t2]), accO[1][td], 0, 0, 0);
            }
        }
        __builtin_amdgcn_s_setprio(0);
    };

    // prologue + 2x-unrolled ping-pong main loop (static buffer roles)
    load_k(0, kA);
    for (int it2 = 0; it2 < 16; ++it2) {
        tile(2*it2,     kA, kB);
        tile(2*it2 + 1, kB, kA);
    }

    // epilogue: reduce denominator across quads (kv partials), normalize, store
#pragma unroll
    for (int qg = 0; qg < 2; ++qg) {
        float s = lpart[qg];
        s += __shfl_xor(s, 16);
        s += __shfl_xor(s, 32);
        float inv = 1.f / s;
        const size_t rowbase =
            (size_t)(blockIdx.z*2048 + q0 + qg*16 + l16)*1024 + blockIdx.y*64;
#pragma unroll
        for (int td = 0; td < 4; ++td)
#pragma unroll
            for (int r = 0; r < 4; ++r)
                ao[rowbase + td*16 + quad*4 + r] = f2bf(accO[qg][td][r] * inv);
    }
}

extern "C" void kernel_launch(void* const* d_in, const int* in_sizes, int n_in,
                              void* d_out, int out_size, void* d_ws, size_t ws_size,
                              hipStream_t stream)
{
    const float* x   = (const float*)d_in[0];
    const float* ctx = (const float*)d_in[1];
    const float* Wq  = (const float*)d_in[2];
    const float* Wk  = (const float*)d_in[3];
    const float* Wv  = (const float*)d_in[4];
    const float* Wo  = (const float*)d_in[5];
    const float* bo  = (const float*)d_in[6];
    float* out = (float*)d_out;

    unsigned short* ws  = (unsigned short*)d_ws;
    unsigned short* xb  = ws;
    unsigned short* cb  = ws + 4194304;
    unsigned short* wT  = ws + 8388608;
    unsigned short* qkv = ws + 12582912;
    unsigned short* ao  = ws;  // reuse xb space (xb dead after projections)

    prep<<<dim3(32, 32, 5), dim3(256), 0, stream>>>(x, ctx, Wq, Wk, Wv, Wo, xb, cb, wT);
    gemm128<<<dim3(32, 8, 3), dim3(256), 0, stream>>>(xb, cb, wT, ao, qkv, bo, out, 0);
    flash_attn<<<dim3(16, 16, 2), dim3(256), 0, stream>>>(qkv, qkv + 4194304, qkv + 8388608, ao);
    gemm_out<<<dim3(32, 16), dim3(256), 0, stream>>>(wT + 3*1048576, ao, bo, out);
}

// Round 6
// 201.025 us; speedup vs baseline: 1.3361x; 1.3361x over previous
//
#include <hip/hip_runtime.h>

// Problem constants
#define B_  2
#define N_  2048
#define M_  2048
#define D_  1024
#define H_  16
#define DH_ 64

typedef __bf16 bf16x8 __attribute__((ext_vector_type(8)));
typedef __bf16 bf16x4 __attribute__((ext_vector_type(4)));
typedef short  short4v __attribute__((ext_vector_type(4)));
typedef float  f32x4  __attribute__((ext_vector_type(4)));
typedef unsigned int u32x4v __attribute__((ext_vector_type(4)));

#define GAS(p) ((__attribute__((address_space(1))) void*)(p))
#define LAS(p) ((__attribute__((address_space(3))) void*)(p))

// SCALE * log2(e), folded into Q at projection time
#define QPRESCALE 0.18033688011112042f

__device__ __forceinline__ unsigned short f2bf(float f) {
    unsigned int u = __builtin_bit_cast(unsigned int, f);
    u += 0x7fffu + ((u >> 16) & 1u);   // round-to-nearest-even
    return (unsigned short)(u >> 16);
}

// pack two f32 -> one u32 of 2 bf16 (lo = a, hi = b), RNE
__device__ __forceinline__ unsigned cvtpkbf(float a, float b) {
    unsigned r;
    asm("v_cvt_pk_bf16_f32 %0, %1, %2" : "=v"(r) : "v"(a), "v"(b));
    return r;
}

// ------- kernel 1: prep = weight transpose+cast (z<4) | input cast (z==4) -------
__global__ __launch_bounds__(256) void prep(
    const float* __restrict__ x, const float* __restrict__ ctx,
    const float* __restrict__ Wq, const float* __restrict__ Wk,
    const float* __restrict__ Wv, const float* __restrict__ Wo,
    unsigned short* __restrict__ xb, unsigned short* __restrict__ cb,
    unsigned short* __restrict__ WTbase)
{
    if (blockIdx.z == 4) {
        int blk = blockIdx.y * 32 + blockIdx.x;
        int stride = 1024 * 256;
        for (int i = blk * 256 + threadIdx.x; i < 2097152; i += stride) {
            const float4* src; unsigned short* dst; int j;
            if (i < 1048576) { src = (const float4*)x;   dst = xb; j = i; }
            else             { src = (const float4*)ctx; dst = cb; j = i - 1048576; }
            float4 v = src[j];
            ushort4 o = make_ushort4(f2bf(v.x), f2bf(v.y), f2bf(v.z), f2bf(v.w));
            *(ushort4*)(dst + 4*j) = o;
        }
        return;
    }
    const float* W = (blockIdx.z == 0) ? Wq : (blockIdx.z == 1) ? Wk
                    : (blockIdx.z == 2) ? Wv : Wo;
    unsigned short* WT = WTbase + (size_t)blockIdx.z * 1048576;
    __shared__ unsigned short t[32][33];
    int tx = threadIdx.x & 31, ty8 = threadIdx.x >> 5;   // 32 x 8
    int c = blockIdx.x * 32 + tx;
#pragma unroll
    for (int i = 0; i < 4; ++i) {
        int r = blockIdx.y * 32 + i*8 + ty8;
        t[i*8 + ty8][tx] = f2bf(W[(size_t)r * 1024 + c]);
    }
    __syncthreads();
    int c2 = blockIdx.y * 32 + tx;
#pragma unroll
    for (int i = 0; i < 4; ++i) {
        int r2 = blockIdx.x * 32 + i*8 + ty8;
        WT[(size_t)r2 * 1024 + c2] = t[tx][i*8 + ty8];
    }
}

// ---------------- kernel 2: 128x128 bf16 GEMM, C = A * Bt^T (QKV modes) -------
// ROUND-6 CHANGE (BK=64): the m97-style 2-phase loop pays a full
// vmcnt(0)+lgkmcnt(0) drain at every __syncthreads (the known ~20% stall of
// this structure).  Double the K-step: stage TWO 32-wide K sub-tiles into
// separate buffers under ONE barrier pair, then run 32 MFMAs.  Halves the
// barrier count (64 -> 32 per block); staging swizzle, summation order
// (k ascending) and occupancy (LDS 32 KB, >=3 blocks/CU) unchanged.
// mode 0: A=WqT, Bt=xb  -> Q^T tile, stored [B,H,N,64] bf16 (*QPRESCALE), ushort4
// mode 1: A=WkT, Bt=cb  -> K^T tile, stored [B,H,M,64] bf16, ushort4
// mode 2: A=cb,  Bt=WvT -> V^T stored [B,H,64,M] bf16, ushort4 (original swap)
__global__ __launch_bounds__(256) void gemm128(
    const unsigned short* __restrict__ xb,
    const unsigned short* __restrict__ cb,
    const unsigned short* __restrict__ wT,
    const unsigned short* __restrict__ aoA,
    unsigned short* __restrict__ qkv_out,
    const float* __restrict__ bo,
    float* __restrict__ outF,
    int base_mode)
{
    __shared__ __align__(16) unsigned short As[2][128*32];
    __shared__ __align__(16) unsigned short Bs[2][128*32];

    const int mode = base_mode + blockIdx.z;
    const unsigned short* Amat;
    const unsigned short* Bt;
    if (mode == 0)      { Amat = wT;               Bt = xb; }
    else if (mode == 1) { Amat = wT + 1048576;     Bt = cb; }
    else if (mode == 2) { Amat = cb;               Bt = wT + 2*1048576; }
    else                { Amat = wT + 3*1048576;   Bt = aoA; }

    const int tid = threadIdx.x;
    const int w = tid >> 6, l = tid & 63;
    const int quad = l >> 4, l16 = l & 15;
    const int wm = w & 1, wn = w >> 1;
    int row0, col0;
    if (mode == 2) { row0 = blockIdx.x * 128; col0 = blockIdx.y * 128; }
    else           { row0 = blockIdx.y * 128; col0 = blockIdx.x * 128; }

    f32x4 acc[4][4];
#pragma unroll
    for (int i = 0; i < 4; ++i)
#pragma unroll
        for (int j = 0; j < 4; ++j) acc[i][j] = (f32x4){0.f, 0.f, 0.f, 0.f};

    for (int k0 = 0; k0 < 1024; k0 += 64) {
        __syncthreads();
#pragma unroll
        for (int h = 0; h < 2; ++h) {
#pragma unroll
            for (int i = 0; i < 2; ++i) {
                int s = i*256 + w*64 + l;
                int m = s >> 2, c = s & 3;
                int cs = c ^ ((m >> 1) & 3);
                __builtin_amdgcn_global_load_lds(
                    GAS(Amat + (size_t)(row0 + m)*1024 + k0 + h*32 + cs*8),
                    LAS(As[h] + (i*256 + w*64)*8), 16, 0, 0);
                __builtin_amdgcn_global_load_lds(
                    GAS(Bt + (size_t)(col0 + m)*1024 + k0 + h*32 + cs*8),
                    LAS(Bs[h] + (i*256 + w*64)*8), 16, 0, 0);
            }
        }
        __syncthreads();

#pragma unroll
        for (int h = 0; h < 2; ++h) {
            bf16x8 af[4], bfr[4];
#pragma unroll
            for (int mt = 0; mt < 4; ++mt) {
                int m = wm*64 + mt*16 + l16;
                af[mt] = *reinterpret_cast<const bf16x8*>(As[h] + m*32 + (quad ^ ((m >> 1) & 3))*8);
                int n = wn*64 + mt*16 + l16;
                bfr[mt] = *reinterpret_cast<const bf16x8*>(Bs[h] + n*32 + (quad ^ ((n >> 1) & 3))*8);
            }
#pragma unroll
            for (int mt = 0; mt < 4; ++mt)
#pragma unroll
                for (int nt = 0; nt < 4; ++nt)
                    acc[mt][nt] = __builtin_amdgcn_mfma_f32_16x16x32_bf16(
                        af[mt], bfr[nt], acc[mt][nt], 0, 0, 0);
        }
    }

    // Epilogues.  C/D layout: col = l16, row = quad*4 + r  [m89/m91 verified]
    if (mode == 2) {
        // V^T: [B,H,64,M]; r-direction = token n -> ushort4
#pragma unroll
        for (int mt = 0; mt < 4; ++mt) {
            int gr = row0 + wm*64 + mt*16 + quad*4;
            int b = gr >> 11, nidx = gr & 2047;
#pragma unroll
            for (int nt = 0; nt < 4; ++nt) {
                int col = col0 + wn*64 + nt*16 + l16;
                int h = col >> 6, d = col & 63;
                ushort4 pk = make_ushort4(f2bf(acc[mt][nt][0]), f2bf(acc[mt][nt][1]),
                                          f2bf(acc[mt][nt][2]), f2bf(acc[mt][nt][3]));
                *(ushort4*)(qkv_out + (size_t)2*4194304
                            + (size_t)((b*16 + h)*64 + d)*2048 + nidx) = pk;
            }
        }
    } else {
        // Q^T/K^T tile: row = channel c=(h,d) (4 consecutive d), col = token n
        const float qs = (mode == 0) ? QPRESCALE : 1.0f;
        unsigned short* obase = qkv_out + (size_t)mode*4194304;
#pragma unroll
        for (int nt = 0; nt < 4; ++nt) {
            int n = col0 + wn*64 + nt*16 + l16;
            int b = n >> 11, nidx = n & 2047;
#pragma unroll
            for (int mt = 0; mt < 4; ++mt) {
                int c = row0 + wm*64 + mt*16 + quad*4;
                int h = c >> 6, d = c & 63;
                ushort4 pkv = make_ushort4(
                    f2bf(acc[mt][nt][0] * qs), f2bf(acc[mt][nt][1] * qs),
                    f2bf(acc[mt][nt][2] * qs), f2bf(acc[mt][nt][3] * qs));
                *(ushort4*)(obase + (size_t)((b*16 + h)*2048 + nidx)*64 + d) = pkv;
            }
        }
    }
}

// ---------------- kernel 2b: out-projection GEMM, 64x128 tile -----------------
__global__ __launch_bounds__(256) void gemm_out(
    const unsigned short* __restrict__ woT,  // [1024 out-ch][1024 in] bf16
    const unsigned short* __restrict__ aoA,  // [4096 tokens][1024] bf16
    const float* __restrict__ bo,
    float* __restrict__ outF)                // [4096 tokens][1024] f32
{
    __shared__ __align__(16) unsigned short As[64*32];
    __shared__ __align__(16) unsigned short Bs[128*32];

    const int tid = threadIdx.x;
    const int w = tid >> 6, l = tid & 63;
    const int quad = l >> 4, l16 = l & 15;
    const int row0 = blockIdx.y * 64;    // out-channel tile
    const int col0 = blockIdx.x * 128;   // token tile

    f32x4 acc[4][2];
#pragma unroll
    for (int i = 0; i < 4; ++i)
#pragma unroll
        for (int j = 0; j < 2; ++j) acc[i][j] = (f32x4){0.f, 0.f, 0.f, 0.f};

    for (int k0 = 0; k0 < 1024; k0 += 32) {
        __syncthreads();
        {
            int m = tid >> 2, c = tid & 3;
            int cs = c ^ ((m >> 1) & 3);
            __builtin_amdgcn_global_load_lds(
                GAS(woT + (size_t)(row0 + m)*1024 + k0 + cs*8),
                LAS(As + (w*64)*8), 16, 0, 0);
        }
#pragma unroll
        for (int i = 0; i < 2; ++i) {
            int s = i*256 + tid;
            int m = s >> 2, c = s & 3;
            int cs = c ^ ((m >> 1) & 3);
            __builtin_amdgcn_global_load_lds(
                GAS(aoA + (size_t)(col0 + m)*1024 + k0 + cs*8),
                LAS(Bs + (i*256 + w*64)*8), 16, 0, 0);
        }
        __syncthreads();

        bf16x8 af[4], bfr[2];
#pragma unroll
        for (int mt = 0; mt < 4; ++mt) {
            int m = mt*16 + l16;
            af[mt] = *reinterpret_cast<const bf16x8*>(As + m*32 + (quad ^ ((m >> 1) & 3))*8);
        }
#pragma unroll
        for (int nt = 0; nt < 2; ++nt) {
            int n = w*32 + nt*16 + l16;
            bfr[nt] = *reinterpret_cast<const bf16x8*>(Bs + n*32 + (quad ^ ((n >> 1) & 3))*8);
        }
#pragma unroll
        for (int mt = 0; mt < 4; ++mt)
#pragma unroll
            for (int nt = 0; nt < 2; ++nt)
                acc[mt][nt] = __builtin_amdgcn_mfma_f32_16x16x32_bf16(
                    af[mt], bfr[nt], acc[mt][nt], 0, 0, 0);
    }

#pragma unroll
    for (int mt = 0; mt < 4; ++mt) {
        int c = row0 + mt*16 + quad*4;
        float4 bv = *(const float4*)(bo + c);
#pragma unroll
        for (int nt = 0; nt < 2; ++nt) {
            int n = col0 + w*32 + nt*16 + l16;
            float4 ov = make_float4(acc[mt][nt][0] + bv.x, acc[mt][nt][1] + bv.y,
                                    acc[mt][nt][2] + bv.z, acc[mt][nt][3] + bv.w);
            *(float4*)(outF + (size_t)n*1024 + c) = ov;
        }
    }
}

// ---------------- kernel 3: flash attention (round-4 LDS version, best) --------
// q-tile 128 (4 waves x 32 q), KV-tile 64, LDS double-buffered.
// Unified K|V slot space per tile:
//   slots [0,576)   = K  64 rows x 9 chunks (72-ushort rows, 8-ushort pad)
//   slots [576,1152)= V^T 64 rows x 9 chunks (72-ushort rows)
// Shift-free softmax (Q carries SCALE*log2e); denominator = per-lane fp32
// partial sums, 2 shuffles at the end.  PV uses native K=32 MFMA via
// cvt_pk + permlane32/16_swap quad-redistribution.
// FAILED VARIANTS (measured): counted-vmcnt/3-buf (r2: null), 64q-per-wave
// (r3: +22%, TLP loss), LDS-free reg-direct K/V (r5: +137%, VMEM path is
// slower than LDS for block-shared data -- LDS staging is a bandwidth
// amplifier, not overhead).  Do not retry those.
__global__ __launch_bounds__(256, 2) void flash_attn(
    const unsigned short* __restrict__ qw,   // [B,H,N,64]  (pre-scaled)
    const unsigned short* __restrict__ kw,   // [B,H,M,64]
    const unsigned short* __restrict__ vtw,  // [B,H,64,M]
    unsigned short* __restrict__ ao)         // [B,N,H*64]
{
    __shared__ __align__(16) unsigned short Tile[2][9216];  // 2 x 18432 B

    const int tid = threadIdx.x;
    const int w = tid >> 6, l = tid & 63;
    const int quad = l >> 4, l16 = l & 15;
    const int bh = blockIdx.z * H_ + blockIdx.y;
    const int q0 = blockIdx.x * 128 + w * 32;   // this wave's 32 queries

    int goff[5];
#pragma unroll
    for (int i = 0; i < 5; ++i) {
        int n = i*256 + w*64 + l;
        int m = (n < 576) ? n : n - 576;
        int row = m / 9, c = m % 9;  if (c > 7) c = 7;     // clamp pad chunk
        goff[i] = (n < 576) ? row*64 + c*8 : row*2048 + c*8;
    }
    const unsigned short* kbase = kw + (size_t)bh*131072;
    const unsigned short* vbase = vtw + (size_t)bh*131072;

    // Q as B-frag (K=32): B[n=q][k=d]; two 16-q groups
    bf16x8 qf[2][2];
#pragma unroll
    for (int qg = 0; qg < 2; ++qg)
#pragma unroll
        for (int s = 0; s < 2; ++s)
            qf[qg][s] = *reinterpret_cast<const bf16x8*>(
                qw + (size_t)(bh*2048 + q0 + qg*16 + l16)*64 + s*32 + quad*8);

    f32x4 accO[2][4];
#pragma unroll
    for (int qg = 0; qg < 2; ++qg)
#pragma unroll
        for (int td = 0; td < 4; ++td) accO[qg][td] = (f32x4){0.f, 0.f, 0.f, 0.f};
    float lpart[2] = {0.f, 0.f};

    const f32x4 zz = (f32x4){0.f, 0.f, 0.f, 0.f};

    // ---- preload tile 0 into buf 0
    {
#pragma unroll
        for (int i = 0; i < 4; ++i) {
            const unsigned short* bp = (i*4 + w < 9) ? kbase : vbase;
            __builtin_amdgcn_global_load_lds(GAS(bp + goff[i]),
                LAS(&Tile[0][(i*256 + w*64)*8]), 16, 0, 0);
        }
        if (w < 2)
            __builtin_amdgcn_global_load_lds(GAS(vbase + goff[4]),
                LAS(&Tile[0][(1024 + w*64)*8]), 16, 0, 0);
    }

    for (int it = 0; it < 32; ++it) {
        __syncthreads();   // drains vmcnt -> Tile[it&1] ready
        const int cur = it & 1;

        if (it + 1 < 32) {
            const unsigned short* kp = kbase + (it+1)*4096;
            const unsigned short* vp = vbase + (it+1)*64;
#pragma unroll
            for (int i = 0; i < 4; ++i) {
                const unsigned short* bp = (i*4 + w < 9) ? kp : vp;
                __builtin_amdgcn_global_load_lds(GAS(bp + goff[i]),
                    LAS(&Tile[cur^1][(i*256 + w*64)*8]), 16, 0, 0);
            }
            if (w < 2)
                __builtin_amdgcn_global_load_lds(GAS(vp + goff[4]),
                    LAS(&Tile[cur^1][(1024 + w*64)*8]), 16, 0, 0);
        }

        const unsigned short* Ks = &Tile[cur][0];
        const unsigned short* Vs = &Tile[cur][4608];

        // S^T = K Q^T : A = K-frag (m=kv), B = Q-frag (n=q); zero-C first MFMA
        f32x4 sac[2][4];
        __builtin_amdgcn_s_setprio(1);
#pragma unroll
        for (int t = 0; t < 4; ++t) {
            const unsigned short* krow = Ks + (t*16 + l16)*72 + quad*8;
            bf16x8 kf0 = *reinterpret_cast<const bf16x8*>(krow);
            bf16x8 kf1 = *reinterpret_cast<const bf16x8*>(krow + 32);
            sac[0][t] = __builtin_amdgcn_mfma_f32_16x16x32_bf16(kf0, qf[0][0], zz, 0, 0, 0);
            sac[1][t] = __builtin_amdgcn_mfma_f32_16x16x32_bf16(kf0, qf[1][0], zz, 0, 0, 0);
            sac[0][t] = __builtin_amdgcn_mfma_f32_16x16x32_bf16(kf1, qf[0][1], sac[0][t], 0, 0, 0);
            sac[1][t] = __builtin_amdgcn_mfma_f32_16x16x32_bf16(kf1, qf[1][1], sac[1][t], 0, 0, 0);
        }
        __builtin_amdgcn_s_setprio(0);

        // P^T = exp2(S^T); per-lane fp32 partial row-sums; build K=32 B-frags
        u32x4v pB[2][2];   // [qg][t2]: words = (e0e1, e2e3, e4e5, e6e7)
#pragma unroll
        for (int qg = 0; qg < 2; ++qg) {
            float s0 = 0.f, s1 = 0.f, s2 = 0.f, s3 = 0.f;
#pragma unroll
            for (int t2 = 0; t2 < 2; ++t2) {
                float pe0 = __builtin_amdgcn_exp2f(sac[qg][2*t2][0]);
                float pe1 = __builtin_amdgcn_exp2f(sac[qg][2*t2][1]);
                float pe2 = __builtin_amdgcn_exp2f(sac[qg][2*t2][2]);
                float pe3 = __builtin_amdgcn_exp2f(sac[qg][2*t2][3]);
                float po0 = __builtin_amdgcn_exp2f(sac[qg][2*t2+1][0]);
                float po1 = __builtin_amdgcn_exp2f(sac[qg][2*t2+1][1]);
                float po2 = __builtin_amdgcn_exp2f(sac[qg][2*t2+1][2]);
                float po3 = __builtin_amdgcn_exp2f(sac[qg][2*t2+1][3]);
                s0 += pe0 + po0; s1 += pe1 + po1;
                s2 += pe2 + po2; s3 += pe3 + po3;
                unsigned b0 = cvtpkbf(pe0, pe1), b1 = cvtpkbf(pe2, pe3);
                unsigned b2 = cvtpkbf(po0, po1), b3 = cvtpkbf(po2, po3);
                asm("v_permlane32_swap_b32 %0, %1" : "+v"(b0), "+v"(b2));
                asm("v_permlane16_swap_b32 %0, %1" : "+v"(b0), "+v"(b2));
                asm("v_permlane32_swap_b32 %0, %1" : "+v"(b1), "+v"(b3));
                asm("v_permlane16_swap_b32 %0, %1" : "+v"(b1), "+v"(b3));
                pB[qg][t2] = (u32x4v){b0, b1, b2, b3};
            }
            lpart[qg] += (s0 + s1) + (s2 + s3);
        }

        // O^T += V^T P^T : A = V^T-frag (m=d, k=kv, K=32), B = P^T (registers)
        __builtin_amdgcn_s_setprio(1);
#pragma unroll
        for (int td = 0; td < 4; ++td) {
            const unsigned short* vrow = Vs + (td*16 + l16)*72 + quad*8;
#pragma unroll
            for (int t2 = 0; t2 < 2; ++t2) {
                bf16x8 vf = *reinterpret_cast<const bf16x8*>(vrow + t2*32);
                accO[0][td] = __builtin_amdgcn_mfma_f32_16x16x32_bf16(
                    vf, __builtin_bit_cast(bf16x8, pB[0][t2]), accO[0][td], 0, 0, 0);
                accO[1][td] = __builtin_amdgcn_mfma_f32_16x16x32_bf16(
                    vf, __builtin_bit_cast(bf16x8, pB[1][t2]), accO[1][td], 0, 0, 0);
            }
        }
        __builtin_amdgcn_s_setprio(0);
    }

    // epilogue: reduce denominator across quads (kv partials), normalize, store
#pragma unroll
    for (int qg = 0; qg < 2; ++qg) {
        float s = lpart[qg];
        s += __shfl_xor(s, 16);
        s += __shfl_xor(s, 32);
        float inv = 1.f / s;
        const size_t rowbase =
            (size_t)(blockIdx.z*2048 + q0 + qg*16 + l16)*1024 + blockIdx.y*64;
#pragma unroll
        for (int td = 0; td < 4; ++td)
#pragma unroll
            for (int r = 0; r < 4; ++r)
                ao[rowbase + td*16 + quad*4 + r] = f2bf(accO[qg][td][r] * inv);
    }
}

extern "C" void kernel_launch(void* const* d_in, const int* in_sizes, int n_in,
                              void* d_out, int out_size, void* d_ws, size_t ws_size,
                              hipStream_t stream)
{
    const float* x   = (const float*)d_in[0];
    const float* ctx = (const float*)d_in[1];
    const float* Wq  = (const float*)d_in[2];
    const float* Wk  = (const float*)d_in[3];
    const float* Wv  = (const float*)d_in[4];
    const float* Wo  = (const float*)d_in[5];
    const float* bo  = (const float*)d_in[6];
    float* out = (float*)d_out;

    unsigned short* ws  = (unsigned short*)d_ws;
    unsigned short* xb  = ws;
    unsigned short* cb  = ws + 4194304;
    unsigned short* wT  = ws + 8388608;
    unsigned short* qkv = ws + 12582912;
    unsigned short* ao  = ws;  // reuse xb space (xb dead after projections)

    prep<<<dim3(32, 32, 5), dim3(256), 0, stream>>>(x, ctx, Wq, Wk, Wv, Wo, xb, cb, wT);
    gemm128<<<dim3(32, 8, 3), dim3(256), 0, stream>>>(xb, cb, wT, ao, qkv, bo, out, 0);
    flash_attn<<<dim3(16, 16, 2), dim3(256), 0, stream>>>(qkv, qkv + 4194304, qkv + 8388608, ao);
    gemm_out<<<dim3(32, 16), dim3(256), 0, stream>>>(wT + 3*1048576, ao, bo, out);
}

// Round 7
// 198.608 us; speedup vs baseline: 1.3524x; 1.0122x over previous
//
#include <hip/hip_runtime.h>

// Problem constants
#define B_  2
#define N_  2048
#define M_  2048
#define D_  1024
#define H_  16
#define DH_ 64

typedef __bf16 bf16x8 __attribute__((ext_vector_type(8)));
typedef __bf16 bf16x4 __attribute__((ext_vector_type(4)));
typedef short  short4v __attribute__((ext_vector_type(4)));
typedef float  f32x4  __attribute__((ext_vector_type(4)));
typedef unsigned int u32x4v __attribute__((ext_vector_type(4)));

#define GAS(p) ((__attribute__((address_space(1))) void*)(p))
#define LAS(p) ((__attribute__((address_space(3))) void*)(p))

// SCALE * log2(e), folded into Q at projection time
#define QPRESCALE 0.18033688011112042f

__device__ __forceinline__ unsigned short f2bf(float f) {
    unsigned int u = __builtin_bit_cast(unsigned int, f);
    u += 0x7fffu + ((u >> 16) & 1u);   // round-to-nearest-even
    return (unsigned short)(u >> 16);
}

// pack two f32 -> one u32 of 2 bf16 (lo = a, hi = b), RNE
__device__ __forceinline__ unsigned cvtpkbf(float a, float b) {
    unsigned r;
    asm("v_cvt_pk_bf16_f32 %0, %1, %2" : "=v"(r) : "v"(a), "v"(b));
    return r;
}

// ------- kernel 1: prep = weight transpose+cast (z<4) | input cast (z==4) -------
__global__ __launch_bounds__(256) void prep(
    const float* __restrict__ x, const float* __restrict__ ctx,
    const float* __restrict__ Wq, const float* __restrict__ Wk,
    const float* __restrict__ Wv, const float* __restrict__ Wo,
    unsigned short* __restrict__ xb, unsigned short* __restrict__ cb,
    unsigned short* __restrict__ WTbase)
{
    if (blockIdx.z == 4) {
        int blk = blockIdx.y * 32 + blockIdx.x;
        int stride = 1024 * 256;
        for (int i = blk * 256 + threadIdx.x; i < 2097152; i += stride) {
            const float4* src; unsigned short* dst; int j;
            if (i < 1048576) { src = (const float4*)x;   dst = xb; j = i; }
            else             { src = (const float4*)ctx; dst = cb; j = i - 1048576; }
            float4 v = src[j];
            ushort4 o = make_ushort4(f2bf(v.x), f2bf(v.y), f2bf(v.z), f2bf(v.w));
            *(ushort4*)(dst + 4*j) = o;
        }
        return;
    }
    const float* W = (blockIdx.z == 0) ? Wq : (blockIdx.z == 1) ? Wk
                    : (blockIdx.z == 2) ? Wv : Wo;
    unsigned short* WT = WTbase + (size_t)blockIdx.z * 1048576;
    __shared__ unsigned short t[32][33];
    int tx = threadIdx.x & 31, ty8 = threadIdx.x >> 5;   // 32 x 8
    int c = blockIdx.x * 32 + tx;
#pragma unroll
    for (int i = 0; i < 4; ++i) {
        int r = blockIdx.y * 32 + i*8 + ty8;
        t[i*8 + ty8][tx] = f2bf(W[(size_t)r * 1024 + c]);
    }
    __syncthreads();
    int c2 = blockIdx.y * 32 + tx;
#pragma unroll
    for (int i = 0; i < 4; ++i) {
        int r2 = blockIdx.x * 32 + i*8 + ty8;
        WT[(size_t)r2 * 1024 + c2] = t[tx][i*8 + ty8];
    }
}

// ---------------- kernel 2: 128x128 bf16 GEMM, C = A * Bt^T (QKV modes) -------
// BK=64 (round-6, measured ~-3us): two 32-wide K sub-tiles staged under one
// barrier pair -> half the vmcnt(0)+lgkmcnt(0) barrier drains.
// mode 0: A=WqT, Bt=xb  -> Q^T tile, stored [B,H,N,64] bf16 (*QPRESCALE), ushort4
// mode 1: A=WkT, Bt=cb  -> K^T tile, stored [B,H,M,64] bf16, ushort4
// mode 2: A=cb,  Bt=WvT -> V^T stored [B,H,64,M] bf16, ushort4 (original swap)
__global__ __launch_bounds__(256) void gemm128(
    const unsigned short* __restrict__ xb,
    const unsigned short* __restrict__ cb,
    const unsigned short* __restrict__ wT,
    const unsigned short* __restrict__ aoA,
    unsigned short* __restrict__ qkv_out,
    const float* __restrict__ bo,
    float* __restrict__ outF,
    int base_mode)
{
    __shared__ __align__(16) unsigned short As[2][128*32];
    __shared__ __align__(16) unsigned short Bs[2][128*32];

    const int mode = base_mode + blockIdx.z;
    const unsigned short* Amat;
    const unsigned short* Bt;
    if (mode == 0)      { Amat = wT;               Bt = xb; }
    else if (mode == 1) { Amat = wT + 1048576;     Bt = cb; }
    else if (mode == 2) { Amat = cb;               Bt = wT + 2*1048576; }
    else                { Amat = wT + 3*1048576;   Bt = aoA; }

    const int tid = threadIdx.x;
    const int w = tid >> 6, l = tid & 63;
    const int quad = l >> 4, l16 = l & 15;
    const int wm = w & 1, wn = w >> 1;
    int row0, col0;
    if (mode == 2) { row0 = blockIdx.x * 128; col0 = blockIdx.y * 128; }
    else           { row0 = blockIdx.y * 128; col0 = blockIdx.x * 128; }

    f32x4 acc[4][4];
#pragma unroll
    for (int i = 0; i < 4; ++i)
#pragma unroll
        for (int j = 0; j < 4; ++j) acc[i][j] = (f32x4){0.f, 0.f, 0.f, 0.f};

    for (int k0 = 0; k0 < 1024; k0 += 64) {
        __syncthreads();
#pragma unroll
        for (int h = 0; h < 2; ++h) {
#pragma unroll
            for (int i = 0; i < 2; ++i) {
                int s = i*256 + w*64 + l;
                int m = s >> 2, c = s & 3;
                int cs = c ^ ((m >> 1) & 3);
                __builtin_amdgcn_global_load_lds(
                    GAS(Amat + (size_t)(row0 + m)*1024 + k0 + h*32 + cs*8),
                    LAS(As[h] + (i*256 + w*64)*8), 16, 0, 0);
                __builtin_amdgcn_global_load_lds(
                    GAS(Bt + (size_t)(col0 + m)*1024 + k0 + h*32 + cs*8),
                    LAS(Bs[h] + (i*256 + w*64)*8), 16, 0, 0);
            }
        }
        __syncthreads();

#pragma unroll
        for (int h = 0; h < 2; ++h) {
            bf16x8 af[4], bfr[4];
#pragma unroll
            for (int mt = 0; mt < 4; ++mt) {
                int m = wm*64 + mt*16 + l16;
                af[mt] = *reinterpret_cast<const bf16x8*>(As[h] + m*32 + (quad ^ ((m >> 1) & 3))*8);
                int n = wn*64 + mt*16 + l16;
                bfr[mt] = *reinterpret_cast<const bf16x8*>(Bs[h] + n*32 + (quad ^ ((n >> 1) & 3))*8);
            }
#pragma unroll
            for (int mt = 0; mt < 4; ++mt)
#pragma unroll
                for (int nt = 0; nt < 4; ++nt)
                    acc[mt][nt] = __builtin_amdgcn_mfma_f32_16x16x32_bf16(
                        af[mt], bfr[nt], acc[mt][nt], 0, 0, 0);
        }
    }

    // Epilogues.  C/D layout: col = l16, row = quad*4 + r  [m89/m91 verified]
    if (mode == 2) {
        // V^T: [B,H,64,M]; r-direction = token n -> ushort4
#pragma unroll
        for (int mt = 0; mt < 4; ++mt) {
            int gr = row0 + wm*64 + mt*16 + quad*4;
            int b = gr >> 11, nidx = gr & 2047;
#pragma unroll
            for (int nt = 0; nt < 4; ++nt) {
                int col = col0 + wn*64 + nt*16 + l16;
                int h = col >> 6, d = col & 63;
                ushort4 pk = make_ushort4(f2bf(acc[mt][nt][0]), f2bf(acc[mt][nt][1]),
                                          f2bf(acc[mt][nt][2]), f2bf(acc[mt][nt][3]));
                *(ushort4*)(qkv_out + (size_t)2*4194304
                            + (size_t)((b*16 + h)*64 + d)*2048 + nidx) = pk;
            }
        }
    } else {
        // Q^T/K^T tile: row = channel c=(h,d) (4 consecutive d), col = token n
        const float qs = (mode == 0) ? QPRESCALE : 1.0f;
        unsigned short* obase = qkv_out + (size_t)mode*4194304;
#pragma unroll
        for (int nt = 0; nt < 4; ++nt) {
            int n = col0 + wn*64 + nt*16 + l16;
            int b = n >> 11, nidx = n & 2047;
#pragma unroll
            for (int mt = 0; mt < 4; ++mt) {
                int c = row0 + wm*64 + mt*16 + quad*4;
                int h = c >> 6, d = c & 63;
                ushort4 pkv = make_ushort4(
                    f2bf(acc[mt][nt][0] * qs), f2bf(acc[mt][nt][1] * qs),
                    f2bf(acc[mt][nt][2] * qs), f2bf(acc[mt][nt][3] * qs));
                *(ushort4*)(obase + (size_t)((b*16 + h)*2048 + nidx)*64 + d) = pkv;
            }
        }
    }
}

// ---------------- kernel 2b: out-projection GEMM, 64x128 tile, BK=64 ----------
// ROUND-7 CHANGE: same BK=64 barrier-halving that won on gemm128 (summation
// order k-ascending unchanged).  LDS 48 KB -> 3 blocks/CU cap; grid 2/CU.
__global__ __launch_bounds__(256) void gemm_out(
    const unsigned short* __restrict__ woT,  // [1024 out-ch][1024 in] bf16
    const unsigned short* __restrict__ aoA,  // [4096 tokens][1024] bf16
    const float* __restrict__ bo,
    float* __restrict__ outF)                // [4096 tokens][1024] f32
{
    __shared__ __align__(16) unsigned short As[2][64*32];
    __shared__ __align__(16) unsigned short Bs[2][128*32];

    const int tid = threadIdx.x;
    const int w = tid >> 6, l = tid & 63;
    const int quad = l >> 4, l16 = l & 15;
    const int row0 = blockIdx.y * 64;    // out-channel tile
    const int col0 = blockIdx.x * 128;   // token tile

    f32x4 acc[4][2];
#pragma unroll
    for (int i = 0; i < 4; ++i)
#pragma unroll
        for (int j = 0; j < 2; ++j) acc[i][j] = (f32x4){0.f, 0.f, 0.f, 0.f};

    for (int k0 = 0; k0 < 1024; k0 += 64) {
        __syncthreads();
#pragma unroll
        for (int h = 0; h < 2; ++h) {
            {
                int m = tid >> 2, c = tid & 3;
                int cs = c ^ ((m >> 1) & 3);
                __builtin_amdgcn_global_load_lds(
                    GAS(woT + (size_t)(row0 + m)*1024 + k0 + h*32 + cs*8),
                    LAS(As[h] + (w*64)*8), 16, 0, 0);
            }
#pragma unroll
            for (int i = 0; i < 2; ++i) {
                int s = i*256 + tid;
                int m = s >> 2, c = s & 3;
                int cs = c ^ ((m >> 1) & 3);
                __builtin_amdgcn_global_load_lds(
                    GAS(aoA + (size_t)(col0 + m)*1024 + k0 + h*32 + cs*8),
                    LAS(Bs[h] + (i*256 + w*64)*8), 16, 0, 0);
            }
        }
        __syncthreads();

#pragma unroll
        for (int h = 0; h < 2; ++h) {
            bf16x8 af[4], bfr[2];
#pragma unroll
            for (int mt = 0; mt < 4; ++mt) {
                int m = mt*16 + l16;
                af[mt] = *reinterpret_cast<const bf16x8*>(As[h] + m*32 + (quad ^ ((m >> 1) & 3))*8);
            }
#pragma unroll
            for (int nt = 0; nt < 2; ++nt) {
                int n = w*32 + nt*16 + l16;
                bfr[nt] = *reinterpret_cast<const bf16x8*>(Bs[h] + n*32 + (quad ^ ((n >> 1) & 3))*8);
            }
#pragma unroll
            for (int mt = 0; mt < 4; ++mt)
#pragma unroll
                for (int nt = 0; nt < 2; ++nt)
                    acc[mt][nt] = __builtin_amdgcn_mfma_f32_16x16x32_bf16(
                        af[mt], bfr[nt], acc[mt][nt], 0, 0, 0);
        }
    }

#pragma unroll
    for (int mt = 0; mt < 4; ++mt) {
        int c = row0 + mt*16 + quad*4;
        float4 bv = *(const float4*)(bo + c);
#pragma unroll
        for (int nt = 0; nt < 2; ++nt) {
            int n = col0 + w*32 + nt*16 + l16;
            float4 ov = make_float4(acc[mt][nt][0] + bv.x, acc[mt][nt][1] + bv.y,
                                    acc[mt][nt][2] + bv.z, acc[mt][nt][3] + bv.w);
            *(float4*)(outF + (size_t)n*1024 + c) = ov;
        }
    }
}

// ---------------- kernel 3: flash attention (kv-split, round-7) ----------------
// ROUND-7 CHANGE (kv-split across wave pairs): previously all 4 waves read
// the IDENTICAL 64 K-rows + V-rows from LDS (4x read duplication; LDS pipe
// ~53% of the iteration wall).  r3 tried to fix this by halving waves and
// lost TLP (+22%).  Now: wave w owns q-half (w&1) [64 q, 4 qg groups] and
// kv-half (w>>1) [32 of 64 kv rows].  Per-wave MFMA/exp2 totals unchanged
// (no compute was duplicated); LDS reads per wave 16 -> 8 b128 (K:4, V:4);
// per-CU LDS reads HALVE at unchanged 8 waves/CU.  Epilogue: one-time
// cross-pair reduction of accO+lpart through the (dead) Tile LDS, then the
// kvh==0 waves normalize+store 64 q each.
// FAILED VARIANTS (do not retry): counted-vmcnt/3-buf (r2 null), 64q/wave
// 2-wave blocks (r3 +22%, TLP loss), LDS-free reg-direct K/V (r5 +137%).
__global__ __launch_bounds__(256, 2) void flash_attn(
    const unsigned short* __restrict__ qw,   // [B,H,N,64]  (pre-scaled)
    const unsigned short* __restrict__ kw,   // [B,H,M,64]
    const unsigned short* __restrict__ vtw,  // [B,H,64,M]
    unsigned short* __restrict__ ao)         // [B,N,H*64]
{
    __shared__ __align__(16) unsigned short Tile[2][9216];  // 2 x 18432 B

    const int tid = threadIdx.x;
    const int w = tid >> 6, l = tid & 63;
    const int quad = l >> 4, l16 = l & 15;
    const int bh = blockIdx.z * H_ + blockIdx.y;
    const int qh = w & 1, kvh = w >> 1;
    const int q0 = blockIdx.x * 128 + qh * 64;   // this wave's 64 queries

    int goff[5];
#pragma unroll
    for (int i = 0; i < 5; ++i) {
        int n = i*256 + w*64 + l;
        int m = (n < 576) ? n : n - 576;
        int row = m / 9, c = m % 9;  if (c > 7) c = 7;     // clamp pad chunk
        goff[i] = (n < 576) ? row*64 + c*8 : row*2048 + c*8;
    }
    const unsigned short* kbase = kw + (size_t)bh*131072;
    const unsigned short* vbase = vtw + (size_t)bh*131072;

    // Q as B-frag (K=32): B[n=q][k=d]; four 16-q groups
    bf16x8 qf[4][2];
#pragma unroll
    for (int qg = 0; qg < 4; ++qg)
#pragma unroll
        for (int s = 0; s < 2; ++s)
            qf[qg][s] = *reinterpret_cast<const bf16x8*>(
                qw + (size_t)(bh*2048 + q0 + qg*16 + l16)*64 + s*32 + quad*8);

    f32x4 accO[4][4];
#pragma unroll
    for (int qg = 0; qg < 4; ++qg)
#pragma unroll
        for (int td = 0; td < 4; ++td) accO[qg][td] = (f32x4){0.f, 0.f, 0.f, 0.f};
    float lpart[4] = {0.f, 0.f, 0.f, 0.f};

    const f32x4 zz = (f32x4){0.f, 0.f, 0.f, 0.f};

    // ---- preload tile 0 into buf 0
    {
#pragma unroll
        for (int i = 0; i < 4; ++i) {
            const unsigned short* bp = (i*4 + w < 9) ? kbase : vbase;
            __builtin_amdgcn_global_load_lds(GAS(bp + goff[i]),
                LAS(&Tile[0][(i*256 + w*64)*8]), 16, 0, 0);
        }
        if (w < 2)
            __builtin_amdgcn_global_load_lds(GAS(vbase + goff[4]),
                LAS(&Tile[0][(1024 + w*64)*8]), 16, 0, 0);
    }

    for (int it = 0; it < 32; ++it) {
        __syncthreads();   // drains vmcnt -> Tile[it&1] ready
        const int cur = it & 1;

        if (it + 1 < 32) {
            const unsigned short* kp = kbase + (it+1)*4096;
            const unsigned short* vp = vbase + (it+1)*64;
#pragma unroll
            for (int i = 0; i < 4; ++i) {
                const unsigned short* bp = (i*4 + w < 9) ? kp : vp;
                __builtin_amdgcn_global_load_lds(GAS(bp + goff[i]),
                    LAS(&Tile[cur^1][(i*256 + w*64)*8]), 16, 0, 0);
            }
            if (w < 2)
                __builtin_amdgcn_global_load_lds(GAS(vp + goff[4]),
                    LAS(&Tile[cur^1][(1024 + w*64)*8]), 16, 0, 0);
        }

        const unsigned short* Ks = &Tile[cur][0];
        const unsigned short* Vs = &Tile[cur][4608];

        // S^T = K Q^T over this wave's 32 kv rows: t = 0,1 (16 rows each)
        f32x4 sac[4][2];
        __builtin_amdgcn_s_setprio(1);
#pragma unroll
        for (int t = 0; t < 2; ++t) {
            const unsigned short* krow = Ks + (kvh*32 + t*16 + l16)*72 + quad*8;
            bf16x8 kf0 = *reinterpret_cast<const bf16x8*>(krow);
            bf16x8 kf1 = *reinterpret_cast<const bf16x8*>(krow + 32);
#pragma unroll
            for (int qg = 0; qg < 4; ++qg) {
                sac[qg][t] = __builtin_amdgcn_mfma_f32_16x16x32_bf16(kf0, qf[qg][0], zz, 0, 0, 0);
                sac[qg][t] = __builtin_amdgcn_mfma_f32_16x16x32_bf16(kf1, qf[qg][1], sac[qg][t], 0, 0, 0);
            }
        }
        __builtin_amdgcn_s_setprio(0);

        // P^T = exp2(S^T); fp32 partial row-sums; build one K=32 B-frag per qg
        // (t=0 rows are the "even" 16, t=1 the "odd" 16 of the 32-window)
        u32x4v pB[4];
#pragma unroll
        for (int qg = 0; qg < 4; ++qg) {
            float pe0 = __builtin_amdgcn_exp2f(sac[qg][0][0]);
            float pe1 = __builtin_amdgcn_exp2f(sac[qg][0][1]);
            float pe2 = __builtin_amdgcn_exp2f(sac[qg][0][2]);
            float pe3 = __builtin_amdgcn_exp2f(sac[qg][0][3]);
            float po0 = __builtin_amdgcn_exp2f(sac[qg][1][0]);
            float po1 = __builtin_amdgcn_exp2f(sac[qg][1][1]);
            float po2 = __builtin_amdgcn_exp2f(sac[qg][1][2]);
            float po3 = __builtin_amdgcn_exp2f(sac[qg][1][3]);
            lpart[qg] += ((pe0 + po0) + (pe1 + po1)) + ((pe2 + po2) + (pe3 + po3));
            unsigned b0 = cvtpkbf(pe0, pe1), b1 = cvtpkbf(pe2, pe3);
            unsigned b2 = cvtpkbf(po0, po1), b3 = cvtpkbf(po2, po3);
            asm("v_permlane32_swap_b32 %0, %1" : "+v"(b0), "+v"(b2));
            asm("v_permlane16_swap_b32 %0, %1" : "+v"(b0), "+v"(b2));
            asm("v_permlane32_swap_b32 %0, %1" : "+v"(b1), "+v"(b3));
            asm("v_permlane16_swap_b32 %0, %1" : "+v"(b1), "+v"(b3));
            pB[qg] = (u32x4v){b0, b1, b2, b3};
        }

        // O^T += V^T P^T over this wave's 32 kv cols (k = kvh*32 + quad*8 + e)
        __builtin_amdgcn_s_setprio(1);
#pragma unroll
        for (int td = 0; td < 4; ++td) {
            bf16x8 vf = *reinterpret_cast<const bf16x8*>(
                Vs + (td*16 + l16)*72 + kvh*32 + quad*8);
#pragma unroll
            for (int qg = 0; qg < 4; ++qg)
                accO[qg][td] = __builtin_amdgcn_mfma_f32_16x16x32_bf16(
                    vf, __builtin_bit_cast(bf16x8, pB[qg]), accO[qg][td], 0, 0, 0);
        }
        __builtin_amdgcn_s_setprio(0);
    }

    // ---- cross-pair (kv-half) reduction through the dead Tile buffer.
    // Layout: per q-half region of 64 lanes x 72 f32 (stride 72, 16B-aligned):
    //   [0..63] = accO (16 x f32x4), [64..67] = lpart.  2 regions = 36 KB.
    float* xch = (float*)&Tile[0][0];
    __syncthreads();   // all waves done reading Tile
    if (kvh == 1) {
        float* base = xch + (size_t)(qh*64 + l)*72;
#pragma unroll
        for (int qg = 0; qg < 4; ++qg)
#pragma unroll
            for (int td = 0; td < 4; ++td)
                *(f32x4*)(base + (qg*4 + td)*4) = accO[qg][td];
        *(f32x4*)(base + 64) = (f32x4){lpart[0], lpart[1], lpart[2], lpart[3]};
    }
    __syncthreads();
    if (kvh == 0) {
        const float* base = xch + (size_t)(qh*64 + l)*72;
#pragma unroll
        for (int qg = 0; qg < 4; ++qg)
#pragma unroll
            for (int td = 0; td < 4; ++td)
                accO[qg][td] += *(const f32x4*)(base + (qg*4 + td)*4);
        f32x4 lp2 = *(const f32x4*)(base + 64);
        lpart[0] += lp2[0]; lpart[1] += lp2[1];
        lpart[2] += lp2[2]; lpart[3] += lp2[3];

        // normalize + store this wave's 64 q rows
#pragma unroll
        for (int qg = 0; qg < 4; ++qg) {
            float s = lpart[qg];
            s += __shfl_xor(s, 16);
            s += __shfl_xor(s, 32);
            float inv = 1.f / s;
            const size_t rowbase =
                (size_t)(blockIdx.z*2048 + q0 + qg*16 + l16)*1024 + blockIdx.y*64;
#pragma unroll
            for (int td = 0; td < 4; ++td)
#pragma unroll
                for (int r = 0; r < 4; ++r)
                    ao[rowbase + td*16 + quad*4 + r] = f2bf(accO[qg][td][r] * inv);
        }
    }
}

extern "C" void kernel_launch(void* const* d_in, const int* in_sizes, int n_in,
                              void* d_out, int out_size, void* d_ws, size_t ws_size,
                              hipStream_t stream)
{
    const float* x   = (const float*)d_in[0];
    const float* ctx = (const float*)d_in[1];
    const float* Wq  = (const float*)d_in[2];
    const float* Wk  = (const float*)d_in[3];
    const float* Wv  = (const float*)d_in[4];
    const float* Wo  = (const float*)d_in[5];
    const float* bo  = (const float*)d_in[6];
    float* out = (float*)d_out;

    unsigned short* ws  = (unsigned short*)d_ws;
    unsigned short* xb  = ws;
    unsigned short* cb  = ws + 4194304;
    unsigned short* wT  = ws + 8388608;
    unsigned short* qkv = ws + 12582912;
    unsigned short* ao  = ws;  // reuse xb space (xb dead after projections)

    prep<<<dim3(32, 32, 5), dim3(256), 0, stream>>>(x, ctx, Wq, Wk, Wv, Wo, xb, cb, wT);
    gemm128<<<dim3(32, 8, 3), dim3(256), 0, stream>>>(xb, cb, wT, ao, qkv, bo, out, 0);
    flash_attn<<<dim3(16, 16, 2), dim3(256), 0, stream>>>(qkv, qkv + 4194304, qkv + 8388608, ao);
    gemm_out<<<dim3(32, 16), dim3(256), 0, stream>>>(wT + 3*1048576, ao, bo, out);
}